// Round 1
// baseline (8682.598 us; speedup 1.0000x reference)
//
#include <hip/hip_runtime.h>

#define NS   48
#define NV   10
#define NEF  144      // 3*NS
#define WN   3364     // W_NUMEL
#define IND  78       // NS + 3*NV
#define NE   100000
#define NN   10000
#define TE   32       // edges per block
#define EPS  1e-5f

// column bases inside w
#define C_SS 0
#define C_VS 2304
#define C_SV 2784
#define C_VV 3264

#define A_SS 0.10206207261596575f   // 1/sqrt(96)
#define A_VS 0.22360679774997896f   // 1/sqrt(20)
#define A_SV 0.10206207261596575f
#define A_VV 0.22360679774997896f
#define RS3  0.5773502691896258f    // 1/sqrt(3)

__device__ __forceinline__ float waveReduceSum(float v) {
    #pragma unroll
    for (int o = 32; o > 0; o >>= 1) v += __shfl_down(v, o, 64);
    return v;
}

// ---------------------------------------------------------------------------
// Fused per-edge kernel: h = relu(EA@W1+b1); contract fc2 on-the-fly with
// xs / dot / xv; atomic scatter into per-node sums.
// ---------------------------------------------------------------------------
__global__ __launch_bounds__(256) void fused_edge_kernel(
    const float* __restrict__ node_attr, const float* __restrict__ edge_attr,
    const float* __restrict__ edge_sh,   const float* __restrict__ W1,
    const float* __restrict__ b1,        const float* __restrict__ W2,
    const float* __restrict__ b2,        const int*   __restrict__ eidx,
    float* __restrict__ sums,            float* __restrict__ cnt)
{
    __shared__ float ea[TE][NEF];
    __shared__ float h[TE][NEF + 4];   // pad to break bank alignment
    __shared__ float xs[TE][NS];
    __shared__ float xv[TE][3][NV];    // [edge][component][vchan]
    __shared__ float dotv[TE][NV];
    __shared__ float s0[TE];
    __shared__ float s1[TE][3];
    __shared__ int   srcs[TE];

    const int t  = threadIdx.x;
    const int e0 = blockIdx.x * TE;

    // ---- phase 0: loads -------------------------------------------------
    for (int idx = t; idx < TE * NEF; idx += 256) {
        int e = idx / NEF, j = idx - e * NEF;
        ea[e][j] = edge_attr[(size_t)(e0 + e) * NEF + j];
    }
    for (int idx = t; idx < TE * IND; idx += 256) {
        int e = idx / IND, j = idx - e * IND;
        int dst = eidx[NE + e0 + e];
        float v = node_attr[(size_t)dst * IND + j];
        if (j < NS) xs[e][j] = v;
        else { int jj = j - NS; xv[e][jj % 3][jj / 3] = v; }
    }
    if (t < TE) {
        int e = t;
        srcs[e]  = eidx[e0 + e];
        s0[e]    = edge_sh[(size_t)(e0 + e) * 4 + 0];
        s1[e][0] = edge_sh[(size_t)(e0 + e) * 4 + 1];
        s1[e][1] = edge_sh[(size_t)(e0 + e) * 4 + 2];
        s1[e][2] = edge_sh[(size_t)(e0 + e) * 4 + 3];
    }
    __syncthreads();

    // ---- phase 1: h = relu(ea @ W1 + b1); dotv --------------------------
    for (int idx = t; idx < TE * NEF; idx += 256) {
        int e = idx / NEF, k = idx - e * NEF;
        float acc = b1[k];
        #pragma unroll 4
        for (int j = 0; j < NEF; ++j) acc += ea[e][j] * W1[j * NEF + k];
        h[e][k] = fmaxf(acc, 0.f);
    }
    for (int idx = t; idx < TE * NV; idx += 256) {
        int e = idx / NV, i = idx - e * NV;
        dotv[e][i] = (xv[e][0][i] * s1[e][0] + xv[e][1][i] * s1[e][1] +
                      xv[e][2][i] * s1[e][2]) * RS3;
    }
    __syncthreads();

    // ---- part A (ss) + part B (vs): out_s[e][o], o < 48 -----------------
    // thread covers edges {eg, eg+16} x outputs {og, og+16, og+32}
    const int eg = t >> 4;
    const int og = t & 15;
    float accA[2][3] = {{0.f,0.f,0.f},{0.f,0.f,0.f}};
    float accB[2][3] = {{0.f,0.f,0.f},{0.f,0.f,0.f}};

    for (int i = 0; i < NS; ++i) {
        const int   base = C_SS + i * NS + og;
        const float bb0 = b2[base], bb1 = b2[base + 16], bb2 = b2[base + 32];
        float w[2][3] = {{bb0, bb1, bb2}, {bb0, bb1, bb2}};
        const float* Fp = W2 + base;
        #pragma unroll 4
        for (int k = 0; k < NEF; ++k) {
            float f0 = Fp[(size_t)k * WN];
            float f1 = Fp[(size_t)k * WN + 16];
            float f2 = Fp[(size_t)k * WN + 32];
            float h0 = h[eg][k], h1 = h[eg + 16][k];
            w[0][0] += h0 * f0; w[0][1] += h0 * f1; w[0][2] += h0 * f2;
            w[1][0] += h1 * f0; w[1][1] += h1 * f1; w[1][2] += h1 * f2;
        }
        float x0 = xs[eg][i], x1 = xs[eg + 16][i];
        accA[0][0] += x0 * w[0][0]; accA[0][1] += x0 * w[0][1]; accA[0][2] += x0 * w[0][2];
        accA[1][0] += x1 * w[1][0]; accA[1][1] += x1 * w[1][1]; accA[1][2] += x1 * w[1][2];
    }
    for (int i = 0; i < NV; ++i) {
        const int   base = C_VS + i * NS + og;
        const float bb0 = b2[base], bb1 = b2[base + 16], bb2 = b2[base + 32];
        float w[2][3] = {{bb0, bb1, bb2}, {bb0, bb1, bb2}};
        const float* Fp = W2 + base;
        #pragma unroll 4
        for (int k = 0; k < NEF; ++k) {
            float f0 = Fp[(size_t)k * WN];
            float f1 = Fp[(size_t)k * WN + 16];
            float f2 = Fp[(size_t)k * WN + 32];
            float h0 = h[eg][k], h1 = h[eg + 16][k];
            w[0][0] += h0 * f0; w[0][1] += h0 * f1; w[0][2] += h0 * f2;
            w[1][0] += h1 * f0; w[1][1] += h1 * f1; w[1][2] += h1 * f2;
        }
        float d0 = dotv[eg][i], d1 = dotv[eg + 16][i];
        accB[0][0] += d0 * w[0][0]; accB[0][1] += d0 * w[0][1]; accB[0][2] += d0 * w[0][2];
        accB[1][0] += d1 * w[1][0]; accB[1][1] += d1 * w[1][1]; accB[1][2] += d1 * w[1][2];
    }
    #pragma unroll
    for (int r = 0; r < 2; ++r) {
        int e = eg + 16 * r;
        int node = srcs[e];
        float sc0 = A_SS * s0[e];
        #pragma unroll
        for (int c = 0; c < 3; ++c) {
            float val = sc0 * accA[r][c] + A_VS * accB[r][c];
            atomicAdd(&sums[(size_t)node * IND + og + 16 * c], val);
        }
    }

    // ---- part C (sv) + part D (vv): out_v[e][o][c], o < 10 --------------
    for (int idx = t; idx < TE * NV; idx += 256) {
        int e = idx / NV, o = idx - e * NV;
        float p = 0.f;
        for (int i = 0; i < NS; ++i) {
            float w = b2[C_SV + i * NV + o];
            const float* Fp = W2 + C_SV + i * NV + o;
            #pragma unroll 4
            for (int k = 0; k < NEF; ++k) w += h[e][k] * Fp[(size_t)k * WN];
            p += xs[e][i] * w;
        }
        float q0 = 0.f, q1 = 0.f, q2 = 0.f;
        for (int i = 0; i < NV; ++i) {
            float w = b2[C_VV + i * NV + o];
            const float* Fp = W2 + C_VV + i * NV + o;
            #pragma unroll 4
            for (int k = 0; k < NEF; ++k) w += h[e][k] * Fp[(size_t)k * WN];
            q0 += xv[e][0][i] * w; q1 += xv[e][1][i] * w; q2 += xv[e][2][i] * w;
        }
        int node = srcs[e];
        float ps = A_SV * p;
        float qs = A_VV * s0[e];
        atomicAdd(&sums[(size_t)node * IND + NS + o * 3 + 0], ps * s1[e][0] + qs * q0);
        atomicAdd(&sums[(size_t)node * IND + NS + o * 3 + 1], ps * s1[e][1] + qs * q1);
        atomicAdd(&sums[(size_t)node * IND + NS + o * 3 + 2], ps * s1[e][2] + qs * q2);
    }
    if (t < TE) atomicAdd(&cnt[srcs[t]], 1.0f);
}

// ---------------------------------------------------------------------------
// out_pre = sums / max(cnt,1) + node_attr   (written into d_out)
// ---------------------------------------------------------------------------
__global__ void finalize_pre(const float* __restrict__ sums,
                             const float* __restrict__ cnt,
                             const float* __restrict__ node_attr,
                             float* __restrict__ out)
{
    int idx = blockIdx.x * 256 + threadIdx.x;
    if (idx >= NN * IND) return;
    int n = idx / IND;
    float c = fmaxf(cnt[n], 1.0f);
    out[idx] = sums[idx] / c + node_attr[idx];
}

// ---------------------------------------------------------------------------
// per-feature stats: blocks 0..47 -> mean/var of scalar cols; 48..57 -> fn
// stats layout: mu[0..48) @0, scale_s[0..48) @64, scale_v[0..10) @128
// ---------------------------------------------------------------------------
__global__ __launch_bounds__(256) void stats_kernel(const float* __restrict__ pre,
                                                    const float* __restrict__ bnw,
                                                    float* __restrict__ stats)
{
    int j = blockIdx.x;
    int t = threadIdx.x;
    float s1 = 0.f, s2 = 0.f;
    if (j < NS) {
        for (int n = t; n < NN; n += 256) {
            float v = pre[(size_t)n * IND + j];
            s1 += v; s2 += v * v;
        }
    } else {
        int vch = j - NS;
        for (int n = t; n < NN; n += 256) {
            float a = pre[(size_t)n * IND + NS + vch * 3 + 0];
            float b = pre[(size_t)n * IND + NS + vch * 3 + 1];
            float c = pre[(size_t)n * IND + NS + vch * 3 + 2];
            s2 += a * a + b * b + c * c;
        }
    }
    __shared__ float r1[4], r2[4];
    s1 = waveReduceSum(s1);
    s2 = waveReduceSum(s2);
    int w = t >> 6, lane = t & 63;
    if (lane == 0) { r1[w] = s1; r2[w] = s2; }
    __syncthreads();
    if (t == 0) {
        float S1 = r1[0] + r1[1] + r1[2] + r1[3];
        float S2 = r2[0] + r2[1] + r2[2] + r2[3];
        if (j < NS) {
            float mu  = S1 / (float)NN;
            float var = S2 / (float)NN - mu * mu;
            stats[j]      = mu;
            stats[64 + j] = bnw[j] * rsqrtf(var + EPS);
        } else {
            int vch = j - NS;
            float fn = S2 / (3.0f * (float)NN);
            stats[128 + vch] = bnw[j] * rsqrtf(fn + EPS);
        }
    }
}

__global__ void normalize_kernel(const float* __restrict__ stats,
                                 const float* __restrict__ bnb,
                                 float* __restrict__ out)
{
    int idx = blockIdx.x * 256 + threadIdx.x;
    if (idx >= NN * IND) return;
    int j = idx % IND;
    float x = out[idx];
    if (j < NS) out[idx] = (x - stats[j]) * stats[64 + j] + bnb[j];
    else        out[idx] = x * stats[128 + (j - NS) / 3];
}

// ---------------------------------------------------------------------------
extern "C" void kernel_launch(void* const* d_in, const int* in_sizes, int n_in,
                              void* d_out, int out_size, void* d_ws, size_t ws_size,
                              hipStream_t stream)
{
    (void)in_sizes; (void)n_in; (void)out_size; (void)ws_size;
    const float* node_attr = (const float*)d_in[0];
    const float* edge_attr = (const float*)d_in[1];
    const float* edge_sh   = (const float*)d_in[2];
    const float* fc1_w     = (const float*)d_in[3];
    const float* fc1_b     = (const float*)d_in[4];
    const float* fc2_w     = (const float*)d_in[5];
    const float* fc2_b     = (const float*)d_in[6];
    const float* bn_w      = (const float*)d_in[7];
    const float* bn_b      = (const float*)d_in[8];
    const int*   eidx      = (const int*)d_in[9];
    float* out   = (float*)d_out;
    float* sums  = (float*)d_ws;                 // NN*IND
    float* cnt   = sums + (size_t)NN * IND;      // NN
    float* stats = cnt + NN;                     // 144 floats

    hipMemsetAsync(d_ws, 0, (size_t)(NN * IND + NN) * sizeof(float), stream);
    fused_edge_kernel<<<NE / TE, 256, 0, stream>>>(node_attr, edge_attr, edge_sh,
                                                   fc1_w, fc1_b, fc2_w, fc2_b,
                                                   eidx, sums, cnt);
    finalize_pre<<<(NN * IND + 255) / 256, 256, 0, stream>>>(sums, cnt, node_attr, out);
    stats_kernel<<<NS + NV, 256, 0, stream>>>(out, bn_w, stats);
    normalize_kernel<<<(NN * IND + 255) / 256, 256, 0, stream>>>(stats, bn_b, out);
}

// Round 3
// 726.538 us; speedup vs baseline: 11.9506x; 11.9506x over previous
//
#include <hip/hip_runtime.h>
#include <hip/hip_bf16.h>

#define NS   48
#define NV   10
#define NEF  144
#define WN   3364
#define IND  78
#define NE   100000
#define NN   10000
#define EPS  1e-5f

#define A_SS 0.10206207261596575f   // 1/sqrt(96)
#define A_VS 0.22360679774997896f   // 1/sqrt(20)
#define A_SV 0.10206207261596575f
#define A_VV 0.22360679774997896f
#define RS3  0.5773502691896258f    // 1/sqrt(3)

#define PITCH 152                   // bf16 row pitch for Abuf/hlds (16B-aligned, 2-way-bank-free)

typedef __attribute__((ext_vector_type(8)))  short  short8;
typedef __attribute__((ext_vector_type(16))) float  f32x16;
typedef __attribute__((ext_vector_type(4)))  int    int4v;
typedef __attribute__((ext_vector_type(4)))  float  float4v;

#define MFMA32(a,b,c) __builtin_amdgcn_mfma_f32_32x32x16_bf16((a),(b),(c),0,0,0)

// ws bf16-region offsets (in shorts, base = (short*)((float*)d_ws + 790160))
#define OFF_W1  0         // 160 x 144
#define OFF_B1  23040     // 64 x 6960   (6912 = 48 i-chunks x 144 k, +48 bias rows)
#define OFF_B2  468480    // 64 x 1456   (1440 + 16 bias)
#define OFF_B3  561664    // 32 x 1456
#define N_PREP  608256

__device__ __forceinline__ short tobf(float v) {
    return __builtin_bit_cast(short, __float2bfloat16(v));
}
__device__ __forceinline__ float fromb(short s) {
    unsigned u = ((unsigned)(unsigned short)s) << 16;
    return __builtin_bit_cast(float, u);
}
__device__ __forceinline__ unsigned pk2(float a, float b) {
    unsigned lo = (unsigned)(unsigned short)tobf(a);
    unsigned hi = (unsigned)(unsigned short)tobf(b);
    return lo | (hi << 16);
}
__device__ __forceinline__ float waveReduceSum(float v) {
    #pragma unroll
    for (int o = 32; o > 0; o >>= 1) v += __shfl_down(v, o, 64);
    return v;
}

// ---------------------------------------------------------------------------
// Weight prep: fp32 -> bf16, transposed n-major / k-contiguous, bias appended
// ---------------------------------------------------------------------------
__global__ void prep_weights(const float* __restrict__ fc1_w,
                             const float* __restrict__ fc2_w,
                             const float* __restrict__ b2,
                             short* __restrict__ wsbf)
{
    int idx = blockIdx.x * 256 + threadIdx.x;
    if (idx >= N_PREP) return;
    float v = 0.f;
    if (idx < OFF_B1) {                       // W1bT[n<160][k<144] = fc1_w[k][n]
        int n = idx / 144, k = idx - n * 144;
        v = (n < 144) ? fc1_w[k * 144 + n] : 0.f;
    } else if (idx < OFF_B2) {                // B1T[n<64][i*144+k | 6912+i]
        int r = idx - OFF_B1; int n = r / 6960, kk = r - n * 6960;
        if (kk < 6912) {
            int i = kk / 144, k = kk - i * 144;
            v = (n < 48) ? fc2_w[(size_t)k * WN + i * 48 + n]
              : (n < 58) ? fc2_w[(size_t)k * WN + 2784 + i * 10 + (n - 48)] : 0.f;
        } else {
            int i = kk - 6912;
            v = (n < 48) ? b2[i * 48 + n]
              : (n < 58) ? b2[2784 + i * 10 + (n - 48)] : 0.f;
        }
    } else if (idx < OFF_B3) {                // B2T[n<64][i*144+k | 1440+i]
        int r = idx - OFF_B2; int n = r / 1456, kk = r - n * 1456;
        if (kk < 1440) {
            int i = kk / 144, k = kk - i * 144;
            v = (n < 48) ? fc2_w[(size_t)k * WN + 2304 + i * 48 + n] : 0.f;
        } else {
            int i = kk - 1440;
            v = (n < 48 && i < 10) ? b2[2304 + i * 48 + n] : 0.f;
        }
    } else {                                  // B3T[n<32][i*144+k | 1440+i]
        int r = idx - OFF_B3; int n = r / 1456, kk = r - n * 1456;
        if (kk < 1440) {
            int i = kk / 144, k = kk - i * 144;
            v = (n < 10) ? fc2_w[(size_t)k * WN + 3264 + i * 10 + n] : 0.f;
        } else {
            int i = kk - 1440;
            v = (n < 10 && i < 10) ? b2[3264 + i * 10 + n] : 0.f;
        }
    }
    wsbf[idx] = tobf(v);
}

// ---------------------------------------------------------------------------
// Fused MFMA kernel: 64 edges/block, 128 threads (2 waves)
// ---------------------------------------------------------------------------
__global__ __launch_bounds__(128) void fused_main(
    const float* __restrict__ node_attr, const float* __restrict__ edge_attr,
    const float* __restrict__ edge_sh,   const float* __restrict__ b1,
    const int*   __restrict__ eidx,      const short* __restrict__ wsbf,
    float* __restrict__ sums,            float* __restrict__ cnt)
{
    __shared__ short Abuf[64 * PITCH];
    __shared__ short hlds[64 * PITCH];
    __shared__ short xf[64 * 96];     // 0..47 xs | 48..57 dot | 58+c*10+i xv
    __shared__ float s0s[64];
    __shared__ float s1s[64][3];
    __shared__ int   srcs[64];

    const short* W1bT = wsbf + OFF_W1;
    const short* B1T  = wsbf + OFF_B1;
    const short* B2T  = wsbf + OFF_B2;
    const short* B3T  = wsbf + OFF_B3;

    const int t    = threadIdx.x;
    const int e0   = blockIdx.x * 64;
    const int lane = t & 63, wave = t >> 6;
    const int n32  = lane & 31, kh = lane >> 5;
    const int et   = t >> 1, half = t & 1;

    // ---- stage edge_sh / srcs ------------------------------------------
    if (t < 64) {
        int ee = e0 + t;
        if (ee < NE) {
            srcs[t] = eidx[ee];
            float4v sh = *reinterpret_cast<const float4v*>(edge_sh + (size_t)ee * 4);
            s0s[t] = sh.x; s1s[t][0] = sh.y; s1s[t][1] = sh.z; s1s[t][2] = sh.w;
        } else {
            srcs[t] = 0; s0s[t] = 0.f; s1s[t][0] = s1s[t][1] = s1s[t][2] = 0.f;
        }
    }
    // ---- stage edge_attr -> Abuf (bf16, A-layout for fc1) --------------
    {
        int ee = min(e0 + et, NE - 1);
        const float* src = edge_attr + (size_t)ee * NEF + half * 72;
        short* dst = Abuf + et * PITCH + half * 72;
        #pragma unroll
        for (int g = 0; g < 9; ++g) {
            float4v a = reinterpret_cast<const float4v*>(src)[2 * g];
            float4v b = reinterpret_cast<const float4v*>(src)[2 * g + 1];
            int4v v = { (int)pk2(a.x, a.y), (int)pk2(a.z, a.w),
                        (int)pk2(b.x, b.y), (int)pk2(b.z, b.w) };
            *reinterpret_cast<int4v*>(dst + g * 8) = v;
        }
    }
    // ---- stage node gather -> xf ---------------------------------------
    for (int idx = t; idx < 64 * IND; idx += 128) {
        int e = idx / IND, j = idx - e * IND;
        int ee = min(e0 + e, NE - 1);
        int dst = eidx[NE + ee];
        float v = node_attr[(size_t)dst * IND + j];
        int slot = (j < NS) ? j : 58 + ((j - NS) % 3) * 10 + (j - NS) / 3;
        xf[e * 96 + slot] = tobf(v);
    }
    __syncthreads();
    // ---- dotv ----------------------------------------------------------
    for (int idx = t; idx < 640; idx += 128) {
        int e = idx / 10, i = idx - e * 10;
        float d = fromb(xf[e * 96 + 58 + i])      * s1s[e][0]
                + fromb(xf[e * 96 + 68 + i])      * s1s[e][1]
                + fromb(xf[e * 96 + 78 + i])      * s1s[e][2];
        xf[e * 96 + 48 + i] = tobf(d * RS3);
    }
    __syncthreads();

    // ---- fc1 GEMM: h = relu(ea @ W1 + b1) -> hlds ----------------------
    for (int pass = 0; pass < 3; ++pass) {
        int ntA = 2 * pass, ntB = 2 * pass + 1;
        bool hasB = (pass < 2);
        f32x16 accA = 0, accB = 0;
        #pragma unroll
        for (int ks = 0; ks < 9; ++ks) {
            short8 a  = *(const short8*)(Abuf + (32 * wave + n32) * PITCH + ks * 16 + kh * 8);
            short8 bA = *(const short8*)(W1bT + (ntA * 32 + n32) * 144 + ks * 16 + kh * 8);
            accA = MFMA32(a, bA, accA);
            if (hasB) {
                short8 bB = *(const short8*)(W1bT + (ntB * 32 + n32) * 144 + ks * 16 + kh * 8);
                accB = MFMA32(a, bB, accB);
            }
        }
        int colA = ntA * 32 + n32, colB = ntB * 32 + n32;
        float b1A = (colA < NEF) ? b1[colA] : 0.f;
        float b1B = (hasB && colB < NEF) ? b1[colB] : 0.f;
        #pragma unroll
        for (int r = 0; r < 16; ++r) {
            int row = (r & 3) + 8 * (r >> 2) + 4 * kh;
            int e = 32 * wave + row;
            if (colA < NEF) hlds[e * PITCH + colA] = tobf(fmaxf(accA[r] + b1A, 0.f));
            if (hasB)       hlds[e * PITCH + colB] = tobf(fmaxf(accB[r] + b1B, 0.f));
        }
        __syncthreads();
    }

    // ---- load h slice to registers (72 fp32 per thread) ----------------
    float hreg[72];
    #pragma unroll
    for (int g = 0; g < 9; ++g) {
        short8 hh = *(const short8*)(hlds + et * PITCH + half * 72 + g * 8);
        #pragma unroll
        for (int j = 0; j < 8; ++j) hreg[g * 8 + j] = fromb(hh[j]);
    }

    // A-chunk generator: Abuf[e][k] = xfac * h[k]
    auto genA = [&](int slot) {
        float xfv = fromb(xf[et * 96 + slot]);
        short* dst = Abuf + et * PITCH + half * 72;
        #pragma unroll
        for (int g = 0; g < 9; ++g) {
            int4v v = { (int)pk2(hreg[g*8+0]*xfv, hreg[g*8+1]*xfv),
                        (int)pk2(hreg[g*8+2]*xfv, hreg[g*8+3]*xfv),
                        (int)pk2(hreg[g*8+4]*xfv, hreg[g*8+5]*xfv),
                        (int)pk2(hreg[g*8+6]*xfv, hreg[g*8+7]*xfv) };
            *reinterpret_cast<int4v*>(dst + g * 8) = v;
        }
    };

    const int arow = (32 * wave + n32) * PITCH + kh * 8;

    // ---- G1: ss + sv (N=64: cols 0..47 out_s-ss, 48..57 p) -------------
    f32x16 acc1a = 0, acc1b = 0, acc2a = 0, acc2b = 0;
    {
        const short* Bb0 = B1T + n32 * 6960 + kh * 8;
        const short* Bb1 = B1T + (32 + n32) * 6960 + kh * 8;
        #pragma unroll 1
        for (int i = 0; i < 48; ++i) {
            __syncthreads();
            genA(i);
            __syncthreads();
            #pragma unroll
            for (int ks = 0; ks < 9; ++ks) {
                short8 a  = *(const short8*)(Abuf + arow + ks * 16);
                short8 b0 = *(const short8*)(Bb0 + i * 144 + ks * 16);
                short8 b1f= *(const short8*)(Bb1 + i * 144 + ks * 16);
                acc1a = MFMA32(a, b0, acc1a);
                acc1b = MFMA32(a, b1f, acc1b);
            }
        }
        // bias block: A = xs (K=48)
        __syncthreads();
        if (half == 0) {
            #pragma unroll
            for (int g = 0; g < 6; ++g)
                *reinterpret_cast<int4v*>(Abuf + et * PITCH + g * 8) =
                    *reinterpret_cast<const int4v*>(xf + et * 96 + g * 8);
        }
        __syncthreads();
        #pragma unroll
        for (int ks = 0; ks < 3; ++ks) {
            short8 a  = *(const short8*)(Abuf + arow + ks * 16);
            short8 b0 = *(const short8*)(Bb0 + 6912 + ks * 16);
            short8 b1f= *(const short8*)(Bb1 + 6912 + ks * 16);
            acc1a = MFMA32(a, b0, acc1a);
            acc1b = MFMA32(a, b1f, acc1b);
        }
    }
    // ---- G2: vs (N=64, cols 0..47 add to out_s) ------------------------
    {
        const short* Bb0 = B2T + n32 * 1456 + kh * 8;
        const short* Bb1 = B2T + (32 + n32) * 1456 + kh * 8;
        #pragma unroll 1
        for (int i = 0; i < 10; ++i) {
            __syncthreads();
            genA(48 + i);
            __syncthreads();
            #pragma unroll
            for (int ks = 0; ks < 9; ++ks) {
                short8 a  = *(const short8*)(Abuf + arow + ks * 16);
                short8 b0 = *(const short8*)(Bb0 + i * 144 + ks * 16);
                short8 b1f= *(const short8*)(Bb1 + i * 144 + ks * 16);
                acc2a = MFMA32(a, b0, acc2a);
                acc2b = MFMA32(a, b1f, acc2b);
            }
        }
        __syncthreads();
        if (half == 0) {
            #pragma unroll
            for (int j = 0; j < 16; ++j)
                Abuf[et * PITCH + j] = (j < 10) ? xf[et * 96 + 48 + j] : (short)0;
        }
        __syncthreads();
        {
            short8 a  = *(const short8*)(Abuf + arow);
            short8 b0 = *(const short8*)(Bb0 + 1440);
            short8 b1f= *(const short8*)(Bb1 + 1440);
            acc2a = MFMA32(a, b0, acc2a);
            acc2b = MFMA32(a, b1f, acc2b);
        }
    }
    // ---- scalar + p epilogue -------------------------------------------
    #pragma unroll
    for (int r = 0; r < 16; ++r) {
        int row = (r & 3) + 8 * (r >> 2) + 4 * kh;
        int e = 32 * wave + row;
        if (e0 + e < NE) {
            float s0e = s0s[e];
            size_t node = (size_t)srcs[e] * IND;
            atomicAdd(&sums[node + n32], A_SS * s0e * acc1a[r] + A_VS * acc2a[r]);
            int col = 32 + n32;
            if (col < 48) {
                atomicAdd(&sums[node + col], A_SS * s0e * acc1b[r] + A_VS * acc2b[r]);
            } else if (col < 58) {
                float p = A_SV * acc1b[r];
                int o = col - 48;
                atomicAdd(&sums[node + 48 + o * 3 + 0], p * s1s[e][0]);
                atomicAdd(&sums[node + 48 + o * 3 + 1], p * s1s[e][1]);
                atomicAdd(&sums[node + 48 + o * 3 + 2], p * s1s[e][2]);
            }
        }
    }
    // ---- G3: vv (per component, N=32, cols 0..9 = q) -------------------
    {
        const short* Bb0 = B3T + n32 * 1456 + kh * 8;
        #pragma unroll 1
        for (int c = 0; c < 3; ++c) {
            f32x16 acc3 = 0;
            #pragma unroll 1
            for (int i = 0; i < 10; ++i) {
                __syncthreads();
                genA(58 + c * 10 + i);
                __syncthreads();
                #pragma unroll
                for (int ks = 0; ks < 9; ++ks) {
                    short8 a  = *(const short8*)(Abuf + arow + ks * 16);
                    short8 b0 = *(const short8*)(Bb0 + i * 144 + ks * 16);
                    acc3 = MFMA32(a, b0, acc3);
                }
            }
            __syncthreads();
            if (half == 0) {
                #pragma unroll
                for (int j = 0; j < 16; ++j)
                    Abuf[et * PITCH + j] = (j < 10) ? xf[et * 96 + 58 + c * 10 + j] : (short)0;
            }
            __syncthreads();
            {
                short8 a  = *(const short8*)(Abuf + arow);
                short8 b0 = *(const short8*)(Bb0 + 1440);
                acc3 = MFMA32(a, b0, acc3);
            }
            if (n32 < 10) {
                #pragma unroll
                for (int r = 0; r < 16; ++r) {
                    int row = (r & 3) + 8 * (r >> 2) + 4 * kh;
                    int e = 32 * wave + row;
                    if (e0 + e < NE)
                        atomicAdd(&sums[(size_t)srcs[e] * IND + 48 + n32 * 3 + c],
                                  A_VV * s0s[e] * acc3[r]);
                }
            }
        }
    }
    if (t < 64 && e0 + t < NE) atomicAdd(&cnt[srcs[t]], 1.0f);
}

// ---------------------------------------------------------------------------
__global__ void finalize_pre(const float* __restrict__ sums,
                             const float* __restrict__ cnt,
                             const float* __restrict__ node_attr,
                             float* __restrict__ out)
{
    int idx = blockIdx.x * 256 + threadIdx.x;
    if (idx >= NN * IND) return;
    int n = idx / IND;
    float c = fmaxf(cnt[n], 1.0f);
    out[idx] = sums[idx] / c + node_attr[idx];
}

__global__ __launch_bounds__(256) void stats_kernel(const float* __restrict__ pre,
                                                    const float* __restrict__ bnw,
                                                    float* __restrict__ stats)
{
    int j = blockIdx.x;
    int t = threadIdx.x;
    float s1 = 0.f, s2 = 0.f;
    if (j < NS) {
        for (int n = t; n < NN; n += 256) {
            float v = pre[(size_t)n * IND + j];
            s1 += v; s2 += v * v;
        }
    } else {
        int vch = j - NS;
        for (int n = t; n < NN; n += 256) {
            float a = pre[(size_t)n * IND + NS + vch * 3 + 0];
            float b = pre[(size_t)n * IND + NS + vch * 3 + 1];
            float c = pre[(size_t)n * IND + NS + vch * 3 + 2];
            s2 += a * a + b * b + c * c;
        }
    }
    __shared__ float r1[4], r2[4];
    s1 = waveReduceSum(s1);
    s2 = waveReduceSum(s2);
    int w = t >> 6, lane = t & 63;
    if (lane == 0) { r1[w] = s1; r2[w] = s2; }
    __syncthreads();
    if (t == 0) {
        float S1 = r1[0] + r1[1] + r1[2] + r1[3];
        float S2 = r2[0] + r2[1] + r2[2] + r2[3];
        if (j < NS) {
            float mu  = S1 / (float)NN;
            float var = S2 / (float)NN - mu * mu;
            stats[j]      = mu;
            stats[64 + j] = bnw[j] * rsqrtf(var + EPS);
        } else {
            int vch = j - NS;
            float fn = S2 / (3.0f * (float)NN);
            stats[128 + vch] = bnw[j] * rsqrtf(fn + EPS);
        }
    }
}

__global__ void normalize_kernel(const float* __restrict__ stats,
                                 const float* __restrict__ bnb,
                                 float* __restrict__ out)
{
    int idx = blockIdx.x * 256 + threadIdx.x;
    if (idx >= NN * IND) return;
    int j = idx % IND;
    float x = out[idx];
    if (j < NS) out[idx] = (x - stats[j]) * stats[64 + j] + bnb[j];
    else        out[idx] = x * stats[128 + (j - NS) / 3];
}

// ---------------------------------------------------------------------------
extern "C" void kernel_launch(void* const* d_in, const int* in_sizes, int n_in,
                              void* d_out, int out_size, void* d_ws, size_t ws_size,
                              hipStream_t stream)
{
    (void)in_sizes; (void)n_in; (void)out_size; (void)ws_size;
    const float* node_attr = (const float*)d_in[0];
    const float* edge_attr = (const float*)d_in[1];
    const float* edge_sh   = (const float*)d_in[2];
    const float* fc1_w     = (const float*)d_in[3];
    const float* fc1_b     = (const float*)d_in[4];
    const float* fc2_w     = (const float*)d_in[5];
    const float* fc2_b     = (const float*)d_in[6];
    const float* bn_w      = (const float*)d_in[7];
    const float* bn_b      = (const float*)d_in[8];
    const int*   eidx      = (const int*)d_in[9];
    float* out   = (float*)d_out;
    float* sums  = (float*)d_ws;                 // 780000
    float* cnt   = sums + (size_t)NN * IND;      // 10000
    float* stats = cnt + NN;                     // 144
    short* wsbf  = (short*)((float*)d_ws + 790160);

    (void)hipMemsetAsync(d_ws, 0, (size_t)(NN * IND + NN) * sizeof(float), stream);
    prep_weights<<<(N_PREP + 255) / 256, 256, 0, stream>>>(fc1_w, fc2_w, fc2_b, wsbf);
    fused_main<<<(NE + 63) / 64, 128, 0, stream>>>(node_attr, edge_attr, edge_sh,
                                                   fc1_b, eidx, wsbf, sums, cnt);
    finalize_pre<<<(NN * IND + 255) / 256, 256, 0, stream>>>(sums, cnt, node_attr, out);
    stats_kernel<<<NS + NV, 256, 0, stream>>>(out, bn_w, stats);
    normalize_kernel<<<(NN * IND + 255) / 256, 256, 0, stream>>>(stats, bn_b, out);
}

// Round 5
// 557.545 us; speedup vs baseline: 15.5729x; 1.3031x over previous
//
#include <hip/hip_runtime.h>
#include <hip/hip_bf16.h>

#define NS   48
#define NV   10
#define NEF  144
#define WN   3364
#define IND  78
#define NE   100000
#define NN   10000
#define EPS  1e-5f
#define HP   144          // hlds pitch (shorts), 288B rows -> 16B aligned

#define A_SS 0.10206207261596575f   // 1/sqrt(96)
#define A_VS 0.22360679774997896f   // 1/sqrt(20)
#define A_SV 0.10206207261596575f
#define A_VV 0.22360679774997896f
#define RS3  0.5773502691896258f    // 1/sqrt(3)

typedef __attribute__((ext_vector_type(8)))  short  short8;
typedef __attribute__((ext_vector_type(16))) float  f32x16;
typedef __attribute__((ext_vector_type(4)))  int    int4v;
typedef __attribute__((ext_vector_type(4)))  float  float4v;
typedef __attribute__((ext_vector_type(2)))  float  float2v;

#define MFMA32(a,b,c) __builtin_amdgcn_mfma_f32_32x32x16_bf16((a),(b),(c),0,0,0)

// ws bf16-region offsets (in shorts, base = (short*)((float*)d_ws + 790160))
#define OFF_W1  0         // 160 x 144
#define OFF_B1  23040     // 64 x 6960   (48 i-chunks x 144 k, +48 bias rows)
#define OFF_B2  468480    // 64 x 1456   (1440 + 16 bias)
#define OFF_B3  561664    // 32 x 1456
#define N_PREP  608256

__device__ __forceinline__ short tobf(float v) {
    return __builtin_bit_cast(short, __float2bfloat16(v));
}
__device__ __forceinline__ float fromb(short s) {
    unsigned u = ((unsigned)(unsigned short)s) << 16;
    return __builtin_bit_cast(float, u);
}
// truncating pack of two f32 -> bf16x2
__device__ __forceinline__ unsigned pkt2(float a, float b) {
    unsigned ua = __builtin_bit_cast(unsigned, a);
    unsigned ub = __builtin_bit_cast(unsigned, b);
    return (ua >> 16) | (ub & 0xFFFF0000u);
}
__device__ __forceinline__ float waveReduceSum(float v) {
    #pragma unroll
    for (int o = 32; o > 0; o >>= 1) v += __shfl_down(v, o, 64);
    return v;
}

// ---------------------------------------------------------------------------
// Weight prep (cold, RN rounding): fp32 -> bf16, n-major / k-contiguous
// ---------------------------------------------------------------------------
__global__ void prep_weights(const float* __restrict__ fc1_w,
                             const float* __restrict__ fc2_w,
                             const float* __restrict__ b2,
                             short* __restrict__ wsbf)
{
    int idx = blockIdx.x * 256 + threadIdx.x;
    if (idx >= N_PREP) return;
    float v = 0.f;
    if (idx < OFF_B1) {                       // W1bT[n<160][k<144] = fc1_w[k][n]
        int n = idx / 144, k = idx - n * 144;
        v = (n < 144) ? fc1_w[k * 144 + n] : 0.f;
    } else if (idx < OFF_B2) {                // B1T[n<64][i*144+k | 6912+i]
        int r = idx - OFF_B1; int n = r / 6960, kk = r - n * 6960;
        if (kk < 6912) {
            int i = kk / 144, k = kk - i * 144;
            v = (n < 48) ? fc2_w[(size_t)k * WN + i * 48 + n]
              : (n < 58) ? fc2_w[(size_t)k * WN + 2784 + i * 10 + (n - 48)] : 0.f;
        } else {
            int i = kk - 6912;
            v = (n < 48) ? b2[i * 48 + n]
              : (n < 58) ? b2[2784 + i * 10 + (n - 48)] : 0.f;
        }
    } else if (idx < OFF_B3) {                // B2T[n<64][i*144+k | 1440+i]
        int r = idx - OFF_B2; int n = r / 1456, kk = r - n * 1456;
        if (kk < 1440) {
            int i = kk / 144, k = kk - i * 144;
            v = (n < 48) ? fc2_w[(size_t)k * WN + 2304 + i * 48 + n] : 0.f;
        } else {
            int i = kk - 1440;
            v = (n < 48 && i < 10) ? b2[2304 + i * 48 + n] : 0.f;
        }
    } else {                                  // B3T[n<32][i*144+k | 1440+i]
        int r = idx - OFF_B3; int n = r / 1456, kk = r - n * 1456;
        if (kk < 1440) {
            int i = kk / 144, k = kk - i * 144;
            v = (n < 10) ? fc2_w[(size_t)k * WN + 3264 + i * 10 + n] : 0.f;
        } else {
            int i = kk - 1440;
            v = (n < 10 && i < 10) ? b2[3264 + i * 10 + n] : 0.f;
        }
    }
    wsbf[idx] = tobf(v);
}

// ---------------------------------------------------------------------------
// Fused MFMA kernel: 64 edges/block, 128 threads (2 waves), barrier-free
// main loops — A-fragments synthesized in registers from h (regs) x x (LDS).
// ---------------------------------------------------------------------------
__global__ __launch_bounds__(128, 2) void fused_main(
    const float* __restrict__ node_attr, const float* __restrict__ edge_attr,
    const float* __restrict__ edge_sh,   const float* __restrict__ b1,
    const int*   __restrict__ eidx,      const short* __restrict__ wsbf,
    float* __restrict__ sums,            float* __restrict__ cnt)
{
    __shared__ short hlds[64 * HP];     // h, bf16, [edge][k]
    __shared__ short xfT[96 * 64];      // transposed: [slot][edge]
    __shared__ float s0s[64];
    __shared__ float s1s[64][3];
    __shared__ int   srcs[64];

    const short* W1bT = wsbf + OFF_W1;
    const short* B1T  = wsbf + OFF_B1;
    const short* B2T  = wsbf + OFF_B2;
    const short* B3T  = wsbf + OFF_B3;

    const int t    = threadIdx.x;
    const int e0   = blockIdx.x * 64;
    const int lane = t & 63, wave = t >> 6;
    const int n32  = lane & 31, kh = lane >> 5;
    const int eL   = 32 * wave + n32;          // lane's edge (local, = A-row)
    const int eLc  = min(e0 + eL, NE - 1);     // clamped global edge

    // ---- zero the tail slots 88..95 (read by G3 bias chunk vs zero-B;
    //      uninitialized LDS can hold NaN patterns and NaN*0 = NaN) ------
    for (int idx = t; idx < 8 * 64; idx += 128) xfT[88 * 64 + idx] = 0;

    // ---- stage edge_sh / srcs ------------------------------------------
    if (t < 64) {
        int ee = e0 + t;
        if (ee < NE) {
            srcs[t] = eidx[ee];
            float4v sh = *reinterpret_cast<const float4v*>(edge_sh + (size_t)ee * 4);
            s0s[t] = sh.x; s1s[t][0] = sh.y; s1s[t][1] = sh.z; s1s[t][2] = sh.w;
        } else {
            srcs[t] = 0; s0s[t] = 0.f; s1s[t][0] = s1s[t][1] = s1s[t][2] = 0.f;
        }
    }

    // ---- node gather -> xfT (thread owns one edge, loops features) -----
    {
        const int eg  = t & 63;
        const int jb  = t >> 6;
        const int egc = min(e0 + eg, NE - 1);
        const int dst = eidx[NE + egc];
        const float* na = node_attr + (size_t)dst * IND;
        for (int j = jb; j < IND; j += 2) {
            int slot = (j < NS) ? j : 58 + ((j - NS) % 3) * 10 + (j - NS) / 3;
            xfT[slot * 64 + eg] = tobf(na[j]);
        }
    }

    // ---- fc1 A-fragments straight from global --------------------------
    short8 afc[9];
    {
        const float* ea = edge_attr + (size_t)eLc * NEF + kh * 8;
        #pragma unroll
        for (int ks = 0; ks < 9; ++ks) {
            float4v lo = *reinterpret_cast<const float4v*>(ea + ks * 16);
            float4v hi = *reinterpret_cast<const float4v*>(ea + ks * 16 + 4);
            int4v v = { (int)pkt2(lo.x, lo.y), (int)pkt2(lo.z, lo.w),
                        (int)pkt2(hi.x, hi.y), (int)pkt2(hi.z, hi.w) };
            afc[ks] = __builtin_bit_cast(short8, v);
        }
    }
    __syncthreads();

    // ---- dotv: slots 48..57 = (xv . s1)/sqrt(3) ------------------------
    #pragma unroll
    for (int it = 0; it < 5; ++it) {
        int e = t & 63;
        int i = (t >> 6) + 2 * it;
        float d = fromb(xfT[(58 + i) * 64 + e]) * s1s[e][0]
                + fromb(xfT[(68 + i) * 64 + e]) * s1s[e][1]
                + fromb(xfT[(78 + i) * 64 + e]) * s1s[e][2];
        xfT[(48 + i) * 64 + e] = tobf(d * RS3);
    }

    // ---- fc1: h = relu(ea @ W1 + b1) -> hlds ---------------------------
    for (int pass = 0; pass < 3; ++pass) {
        int ntA = 2 * pass, ntB = 2 * pass + 1;
        bool hasB = (pass < 2);
        f32x16 accA = 0, accB = 0;
        #pragma unroll
        for (int ks = 0; ks < 9; ++ks) {
            short8 bA = *(const short8*)(W1bT + (ntA * 32 + n32) * 144 + ks * 16 + kh * 8);
            accA = MFMA32(afc[ks], bA, accA);
            if (hasB) {
                short8 bB = *(const short8*)(W1bT + (ntB * 32 + n32) * 144 + ks * 16 + kh * 8);
                accB = MFMA32(afc[ks], bB, accB);
            }
        }
        int colA = ntA * 32 + n32, colB = ntB * 32 + n32;
        float b1A = (colA < NEF) ? b1[colA] : 0.f;
        float b1B = (hasB && colB < NEF) ? b1[colB] : 0.f;
        #pragma unroll
        for (int r = 0; r < 16; ++r) {
            int row = (r & 3) + 8 * (r >> 2) + 4 * kh;
            int e = 32 * wave + row;
            if (colA < NEF) hlds[e * HP + colA] = tobf(fmaxf(accA[r] + b1A, 0.f));
            if (hasB)       hlds[e * HP + colB] = tobf(fmaxf(accB[r] + b1B, 0.f));
        }
    }
    __syncthreads();

    // ---- h slice to registers as f32 pairs (for v_pk_mul_f32) ----------
    float2v hreg[36];
    #pragma unroll
    for (int ks = 0; ks < 9; ++ks) {
        int4v hh = *(const int4v*)(hlds + eL * HP + ks * 16 + kh * 8);
        #pragma unroll
        for (int q = 0; q < 4; ++q) {
            unsigned u = (unsigned)hh[q];
            float2v p;
            p.x = __builtin_bit_cast(float, u << 16);
            p.y = __builtin_bit_cast(float, u & 0xFFFF0000u);
            hreg[ks * 4 + q] = p;
        }
    }

    const int eoff = eL;  // xfT column for this lane

    // ---- G1: ss + sv (N=64: cols 0..47 out_s-ss, 48..57 p) -------------
    f32x16 acc1a = 0, acc1b = 0, acc2a = 0, acc2b = 0;
    {
        const short* Bb0 = B1T + n32 * 6960 + kh * 8;
        const short* Bb1 = B1T + (32 + n32) * 6960 + kh * 8;
        #pragma unroll 1
        for (int i = 0; i < 48; ++i) {
            float xv = fromb(xfT[i * 64 + eoff]);
            float2v x2; x2.x = xv; x2.y = xv;
            const short* p0 = Bb0 + i * 144;
            const short* p1 = Bb1 + i * 144;
            #pragma unroll
            for (int ks = 0; ks < 9; ++ks) {
                int4v v;
                #pragma unroll
                for (int q = 0; q < 4; ++q) {
                    float2v pr = hreg[ks * 4 + q] * x2;
                    v[q] = (int)pkt2(pr.x, pr.y);
                }
                short8 a  = __builtin_bit_cast(short8, v);
                short8 b0 = *(const short8*)(p0 + ks * 16);
                short8 b1f= *(const short8*)(p1 + ks * 16);
                acc1a = MFMA32(a, b0, acc1a);
                acc1b = MFMA32(a, b1f, acc1b);
            }
        }
        // bias chunks: A = xs (K=48), direct from xfT
        #pragma unroll
        for (int ks = 0; ks < 3; ++ks) {
            short8 a;
            #pragma unroll
            for (int j = 0; j < 8; ++j)
                a[j] = xfT[(ks * 16 + kh * 8 + j) * 64 + eoff];
            short8 b0 = *(const short8*)(Bb0 + 6912 + ks * 16);
            short8 b1f= *(const short8*)(Bb1 + 6912 + ks * 16);
            acc1a = MFMA32(a, b0, acc1a);
            acc1b = MFMA32(a, b1f, acc1b);
        }
    }
    // ---- G2: vs (N=64, cols 0..47 add to out_s) ------------------------
    {
        const short* Bb0 = B2T + n32 * 1456 + kh * 8;
        const short* Bb1 = B2T + (32 + n32) * 1456 + kh * 8;
        #pragma unroll 1
        for (int i = 0; i < 10; ++i) {
            float xv = fromb(xfT[(48 + i) * 64 + eoff]);
            float2v x2; x2.x = xv; x2.y = xv;
            const short* p0 = Bb0 + i * 144;
            const short* p1 = Bb1 + i * 144;
            #pragma unroll
            for (int ks = 0; ks < 9; ++ks) {
                int4v v;
                #pragma unroll
                for (int q = 0; q < 4; ++q) {
                    float2v pr = hreg[ks * 4 + q] * x2;
                    v[q] = (int)pkt2(pr.x, pr.y);
                }
                short8 a  = __builtin_bit_cast(short8, v);
                short8 b0 = *(const short8*)(p0 + ks * 16);
                short8 b1f= *(const short8*)(p1 + ks * 16);
                acc2a = MFMA32(a, b0, acc2a);
                acc2b = MFMA32(a, b1f, acc2b);
            }
        }
        // bias chunk: A = dot (k<10; slots 58..63 hold real xv floats,
        // B rows k>=10 are zero -> contribution zero, no NaN risk)
        {
            short8 a;
            #pragma unroll
            for (int j = 0; j < 8; ++j)
                a[j] = xfT[(48 + kh * 8 + j) * 64 + eoff];
            short8 b0 = *(const short8*)(Bb0 + 1440);
            short8 b1f= *(const short8*)(Bb1 + 1440);
            acc2a = MFMA32(a, b0, acc2a);
            acc2b = MFMA32(a, b1f, acc2b);
        }
    }
    // ---- scalar + p epilogue -------------------------------------------
    #pragma unroll
    for (int r = 0; r < 16; ++r) {
        int row = (r & 3) + 8 * (r >> 2) + 4 * kh;
        int e = 32 * wave + row;
        if (e0 + e < NE) {
            float s0e = s0s[e];
            size_t node = (size_t)srcs[e] * IND;
            atomicAdd(&sums[node + n32], A_SS * s0e * acc1a[r] + A_VS * acc2a[r]);
            int col = 32 + n32;
            if (col < 48) {
                atomicAdd(&sums[node + col], A_SS * s0e * acc1b[r] + A_VS * acc2b[r]);
            } else if (col < 58) {
                float p = A_SV * acc1b[r];
                int o = col - 48;
                atomicAdd(&sums[node + 48 + o * 3 + 0], p * s1s[e][0]);
                atomicAdd(&sums[node + 48 + o * 3 + 1], p * s1s[e][1]);
                atomicAdd(&sums[node + 48 + o * 3 + 2], p * s1s[e][2]);
            }
        }
    }
    // ---- G3: vv (per component, N=32, cols 0..9 = q) -------------------
    {
        const short* Bb0 = B3T + n32 * 1456 + kh * 8;
        #pragma unroll 1
        for (int c = 0; c < 3; ++c) {
            f32x16 acc3 = 0;
            #pragma unroll 1
            for (int i = 0; i < 10; ++i) {
                float xv = fromb(xfT[(58 + c * 10 + i) * 64 + eoff]);
                float2v x2; x2.x = xv; x2.y = xv;
                const short* p0 = Bb0 + i * 144;
                #pragma unroll
                for (int ks = 0; ks < 9; ++ks) {
                    int4v v;
                    #pragma unroll
                    for (int q = 0; q < 4; ++q) {
                        float2v pr = hreg[ks * 4 + q] * x2;
                        v[q] = (int)pkt2(pr.x, pr.y);
                    }
                    short8 a  = __builtin_bit_cast(short8, v);
                    short8 b0 = *(const short8*)(p0 + ks * 16);
                    acc3 = MFMA32(a, b0, acc3);
                }
            }
            // bias chunk: A = xv[c] (k<10; tail slots zeroed above)
            {
                short8 a;
                #pragma unroll
                for (int j = 0; j < 8; ++j)
                    a[j] = xfT[(58 + c * 10 + kh * 8 + j) * 64 + eoff];
                short8 b0 = *(const short8*)(Bb0 + 1440);
                acc3 = MFMA32(a, b0, acc3);
            }
            if (n32 < 10) {
                #pragma unroll
                for (int r = 0; r < 16; ++r) {
                    int row = (r & 3) + 8 * (r >> 2) + 4 * kh;
                    int e = 32 * wave + row;
                    if (e0 + e < NE)
                        atomicAdd(&sums[(size_t)srcs[e] * IND + 48 + n32 * 3 + c],
                                  A_VV * s0s[e] * acc3[r]);
                }
            }
        }
    }
    if (t < 64 && e0 + t < NE) atomicAdd(&cnt[srcs[t]], 1.0f);
}

// ---------------------------------------------------------------------------
// stats over pre = sums/max(cnt,1) + node_attr (finalize fused in)
// ---------------------------------------------------------------------------
__global__ __launch_bounds__(256) void stats_kernel(const float* __restrict__ sums,
                                                    const float* __restrict__ cnt,
                                                    const float* __restrict__ node_attr,
                                                    const float* __restrict__ bnw,
                                                    float* __restrict__ stats)
{
    int j = blockIdx.x;
    int t = threadIdx.x;
    float s1 = 0.f, s2 = 0.f;
    if (j < NS) {
        for (int n = t; n < NN; n += 256) {
            float c = fmaxf(cnt[n], 1.0f);
            size_t idx = (size_t)n * IND + j;
            float v = sums[idx] / c + node_attr[idx];
            s1 += v; s2 += v * v;
        }
    } else {
        int vch = j - NS;
        for (int n = t; n < NN; n += 256) {
            float c = fmaxf(cnt[n], 1.0f);
            size_t base = (size_t)n * IND + NS + vch * 3;
            float a = sums[base + 0] / c + node_attr[base + 0];
            float b = sums[base + 1] / c + node_attr[base + 1];
            float d = sums[base + 2] / c + node_attr[base + 2];
            s2 += a * a + b * b + d * d;
        }
    }
    __shared__ float r1[4], r2[4];
    s1 = waveReduceSum(s1);
    s2 = waveReduceSum(s2);
    int w = t >> 6, lane = t & 63;
    if (lane == 0) { r1[w] = s1; r2[w] = s2; }
    __syncthreads();
    if (t == 0) {
        float S1 = r1[0] + r1[1] + r1[2] + r1[3];
        float S2 = r2[0] + r2[1] + r2[2] + r2[3];
        if (j < NS) {
            float mu  = S1 / (float)NN;
            float var = S2 / (float)NN - mu * mu;
            stats[j]      = mu;
            stats[64 + j] = bnw[j] * rsqrtf(var + EPS);
        } else {
            int vch = j - NS;
            float fn = S2 / (3.0f * (float)NN);
            stats[128 + vch] = bnw[j] * rsqrtf(fn + EPS);
        }
    }
}

__global__ void normalize_kernel(const float* __restrict__ sums,
                                 const float* __restrict__ cnt,
                                 const float* __restrict__ node_attr,
                                 const float* __restrict__ stats,
                                 const float* __restrict__ bnb,
                                 float* __restrict__ out)
{
    int idx = blockIdx.x * 256 + threadIdx.x;
    if (idx >= NN * IND) return;
    int n = idx / IND;
    int j = idx - n * IND;
    float c = fmaxf(cnt[n], 1.0f);
    float x = sums[idx] / c + node_attr[idx];
    if (j < NS) out[idx] = (x - stats[j]) * stats[64 + j] + bnb[j];
    else        out[idx] = x * stats[128 + (j - NS) / 3];
}

// ---------------------------------------------------------------------------
extern "C" void kernel_launch(void* const* d_in, const int* in_sizes, int n_in,
                              void* d_out, int out_size, void* d_ws, size_t ws_size,
                              hipStream_t stream)
{
    (void)in_sizes; (void)n_in; (void)out_size; (void)ws_size;
    const float* node_attr = (const float*)d_in[0];
    const float* edge_attr = (const float*)d_in[1];
    const float* edge_sh   = (const float*)d_in[2];
    const float* fc1_w     = (const float*)d_in[3];
    const float* fc1_b     = (const float*)d_in[4];
    const float* fc2_w     = (const float*)d_in[5];
    const float* fc2_b     = (const float*)d_in[6];
    const float* bn_w      = (const float*)d_in[7];
    const float* bn_b      = (const float*)d_in[8];
    const int*   eidx      = (const int*)d_in[9];
    float* out   = (float*)d_out;
    float* sums  = (float*)d_ws;                 // 780000
    float* cnt   = sums + (size_t)NN * IND;      // 10000
    float* stats = cnt + NN;                     // 144
    short* wsbf  = (short*)((float*)d_ws + 790160);

    (void)hipMemsetAsync(d_ws, 0, (size_t)(NN * IND + NN) * sizeof(float), stream);
    prep_weights<<<(N_PREP + 255) / 256, 256, 0, stream>>>(fc1_w, fc2_w, fc2_b, wsbf);
    fused_main<<<(NE + 63) / 64, 128, 0, stream>>>(node_attr, edge_attr, edge_sh,
                                                   fc1_b, eidx, wsbf, sums, cnt);
    stats_kernel<<<NS + NV, 256, 0, stream>>>(sums, cnt, node_attr, bn_w, stats);
    normalize_kernel<<<(NN * IND + 255) / 256, 256, 0, stream>>>(sums, cnt, node_attr,
                                                                 stats, bn_b, out);
}